// Round 1
// baseline (1851.559 us; speedup 1.0000x reference)
//
#include <hip/hip_runtime.h>
#include <math.h>

#define R2C 0.70710678118654752440f

// ---------------- workspace layout (bytes) ----------------
// u_f : 2049*8192*8  = 134,283,264   at 0          (later: yout, 268,435,456 B over u_f+v_f)
// v_f : 134,283,264                  at OFS_VF
// y_f : 2049*16384*8 = 268,566,528   at OFS_YF     (Xt aliases here before GEMM, 134,217,728 B)
// tw2k: 1024 float2                  at OFS_TW2K
// tw4k: 2049 float2                  at OFS_TW4K
#define OFS_VF   134283264ull
#define OFS_YF   268566528ull
#define OFS_TW2K 537133056ull
#define OFS_TW4K 537141248ull

__device__ __forceinline__ float2 cmulf(float2 a, float2 b){
  return make_float2(a.x*b.x - a.y*b.y, a.x*b.y + a.y*b.x);
}
__device__ __forceinline__ float2 caddf(float2 a, float2 b){ return make_float2(a.x+b.x, a.y+b.y); }
__device__ __forceinline__ float2 csubf(float2 a, float2 b){ return make_float2(a.x-b.x, a.y-b.y); }

// multiply by -i (forward) / +i (inverse)
template<int INV>
__device__ __forceinline__ float2 rot90(float2 a){
  return INV ? make_float2(-a.y, a.x) : make_float2(a.y, -a.x);
}
template<int INV>
__device__ __forceinline__ float2 twld(const float2* __restrict__ tw, int idx){
  float2 w = tw[idx];
  return INV ? make_float2(w.x, -w.y) : w;
}

// ---------------- twiddle init ----------------
__global__ void tw_init(float2* tw2k, float2* tw4k){
  int t = blockIdx.x*256 + threadIdx.x;
  if (t < 1024){
    double th = -6.283185307179586476925286766559 * (double)t / 2048.0;
    tw2k[t] = make_float2((float)cos(th), (float)sin(th));
  }
  if (t < 2049){
    double th = -6.283185307179586476925286766559 * (double)t / 4096.0;
    tw4k[t] = make_float2((float)cos(th), (float)sin(th));
  }
}

// ---------------- decimation transpose: X[b][c][ni*16+ti] -> Xt[(ti*8+b)*64+c][ni] ----------------
__global__ __launch_bounds__(64) void decimate_x(const float* __restrict__ X, float* __restrict__ Xt){
  __shared__ __align__(16) float tile[16*260];   // [ti][ni] padded
  int blk = blockIdx.x;
  int nc = blk & 15, c = (blk>>4) & 63, bi = blk>>10;
  const float* src = X + ((size_t)(bi*64 + c))*65536 + (size_t)nc*4096;
  int t = threadIdx.x;  // 64
  for (int k = 0; k < 16; k++){
    float4 v = *(const float4*)&src[4*(t + (k<<6))];
    int j = 4*(t + (k<<6));
    int ni = j >> 4;            // 0..255
    int ti0 = j & 15;           // 0,4,8,12
    tile[(ti0+0)*260 + ni] = v.x;
    tile[(ti0+1)*260 + ni] = v.y;
    tile[(ti0+2)*260 + ni] = v.z;
    tile[(ti0+3)*260 + ni] = v.w;
  }
  __syncthreads();
  for (int ti = 0; ti < 16; ti++){
    float4 v = *(const float4*)&tile[ti*260 + 4*t];
    size_t s = (size_t)((ti*8 + bi)*64 + c);
    *(float4*)&Xt[s*4096 + nc*256 + 4*t] = v;
  }
}

// ---------------- 2048-pt complex FFT core (DIT, bit-reversed input in LDS) ----------------
// radix-8 first pass (stages 1-3, trivial twiddles) + fused radix-2 pairs (4,5)(6,7)(8,9)(10,11)
template<int INV>
__device__ void fft2048(float2* Zq, int tl, const float2* __restrict__ tw2k){
  {
    const float2 W81 = INV ? make_float2(R2C,  R2C) : make_float2(R2C, -R2C);
    const float2 W83 = INV ? make_float2(-R2C, R2C) : make_float2(-R2C, -R2C);
    for (int r = 0; r < 4; r++){
      float4* p4 = (float4*)(Zq + ((tl + (r<<6)) << 3));
      float4 v0 = p4[0], v1 = p4[1], v2 = p4[2], v3 = p4[3];
      float2 a0 = make_float2(v0.x,v0.y), a1 = make_float2(v0.z,v0.w);
      float2 a2 = make_float2(v1.x,v1.y), a3 = make_float2(v1.z,v1.w);
      float2 a4 = make_float2(v2.x,v2.y), a5 = make_float2(v2.z,v2.w);
      float2 a6 = make_float2(v3.x,v3.y), a7 = make_float2(v3.z,v3.w);
      float2 b0 = caddf(a0,a1), b1 = csubf(a0,a1);
      float2 b2 = caddf(a2,a3), b3 = csubf(a2,a3);
      float2 b4 = caddf(a4,a5), b5 = csubf(a4,a5);
      float2 b6 = caddf(a6,a7), b7 = csubf(a6,a7);
      float2 c0 = caddf(b0,b2), c2 = csubf(b0,b2);
      float2 tt = rot90<INV>(b3);
      float2 c1 = caddf(b1,tt), c3 = csubf(b1,tt);
      float2 c4 = caddf(b4,b6), c6 = csubf(b4,b6);
      tt = rot90<INV>(b7);
      float2 c5 = caddf(b5,tt), c7 = csubf(b5,tt);
      float2 d0 = caddf(c0,c4), d4 = csubf(c0,c4);
      tt = cmulf(W81, c5);
      float2 d1 = caddf(c1,tt), d5 = csubf(c1,tt);
      tt = rot90<INV>(c6);
      float2 d2 = caddf(c2,tt), d6 = csubf(c2,tt);
      tt = cmulf(W83, c7);
      float2 d3 = caddf(c3,tt), d7 = csubf(c3,tt);
      p4[0] = make_float4(d0.x,d0.y,d1.x,d1.y);
      p4[1] = make_float4(d2.x,d2.y,d3.x,d3.y);
      p4[2] = make_float4(d4.x,d4.y,d5.x,d5.y);
      p4[3] = make_float4(d6.x,d6.y,d7.x,d7.y);
    }
  }
  __syncthreads();
  #pragma unroll
  for (int s = 4; s <= 10; s += 2){
    const int hh = 1 << (s-1);
    const int sh2 = 11 - s, sh4 = 10 - s;
    for (int r = 0; r < 8; r++){
      int fm = tl + (r<<6);                 // 0..511
      int j  = fm & (hh-1);
      int i0 = ((fm >> (s-1)) << (s+1)) + j;
      float2 a = Zq[i0], b = Zq[i0+hh], c = Zq[i0+2*hh], d = Zq[i0+3*hh];
      float2 Wa = twld<INV>(tw2k, j << sh2);
      float2 Wb = twld<INV>(tw2k, j << sh4);
      float2 wb = cmulf(Wa,b), wd = cmulf(Wa,d);
      float2 t0 = caddf(a,wb), t1 = csubf(a,wb);
      float2 t2 = caddf(c,wd), t3 = csubf(c,wd);
      float2 u0 = cmulf(Wb,t2);
      float2 u1 = rot90<INV>(cmulf(Wb,t3));
      Zq[i0]      = caddf(t0,u0);
      Zq[i0+2*hh] = csubf(t0,u0);
      Zq[i0+hh]   = caddf(t1,u1);
      Zq[i0+3*hh] = csubf(t1,u1);
    }
    __syncthreads();
  }
}

// ---------------- forward real-4096 FFT: 4 signals/block, output bin-major dst[n*8192 + s] ----------------
__global__ __launch_bounds__(256) void fft_fwd(
    const float* __restrict__ src, int row_len, int conj_out,
    float2* __restrict__ dst,
    const float2* __restrict__ tw2k, const float2* __restrict__ tw4k)
{
  __shared__ __align__(16) float2 Z[4*2048];   // 64 KB
  const int t = threadIdx.x;
  const int q = t >> 6, tl = t & 63;
  const size_t s = (size_t)blockIdx.x*4 + q;
  float2* Zq = Z + (q << 11);
  if (row_len == 4096){
    const float2* xp = (const float2*)(src + s*4096);
    for (int k = 0; k < 32; k++){
      int j = tl + (k<<6);
      Zq[__brev((unsigned)j) >> 21] = xp[j];
    }
  } else {
    const float* xp = src + s*(size_t)row_len;
    for (int k = 0; k < 32; k++){
      int j = tl + (k<<6);
      int j2 = j << 1;
      float x0 = (j2     < row_len) ? xp[j2]   : 0.f;
      float x1 = (j2 + 1 < row_len) ? xp[j2+1] : 0.f;
      Zq[__brev((unsigned)j) >> 21] = make_float2(x0, x1);
    }
  }
  __syncthreads();
  fft2048<0>(Zq, tl, tw2k);
  // Hermitian un-pack: X[n] = E + W_n*O ; store bins 0..2047, tail 2048
  const size_t base = (size_t)blockIdx.x*4;
  for (int it = 0; it < 32; it++){
    int idx = (it<<8) + t;
    int n = idx >> 2, qq = idx & 3;
    const float2* Zs = Z + (qq << 11);
    float2 P = Zs[n];
    float2 Q = Zs[(2048 - n) & 2047];
    float2 W = tw4k[n];
    float Ex = 0.5f*(P.x + Q.x), Ey = 0.5f*(P.y - Q.y);
    float Dx = 0.5f*(P.x - Q.x), Dy = 0.5f*(P.y + Q.y);
    float WDx = W.x*Dx - W.y*Dy;
    float WDy = W.x*Dy + W.y*Dx;
    float2 Xn = make_float2(Ex + WDy, conj_out ? (WDx - Ey) : (Ey - WDx));
    dst[(size_t)n*8192 + base + qq] = Xn;
  }
  if (t < 4){
    float2 Z0 = Z[t << 11];
    dst[2048ull*8192 + base + t] = make_float2(Z0.x - Z0.y, 0.f);   // Nyquist (real)
  }
}

// ---------------- per-bin complex GEMM: Y[n][tb][h] = sum_c U[n][tb][c] * V[n][h][c] ----------------
// block: 64 tb-rows (I half) x 128 h-cols, c in 2 halves of 32; 4x8 complex acc/thread
__global__ __launch_bounds__(256) void gemm_bins(
    const float2* __restrict__ uf, const float2* __restrict__ vf,
    float2* __restrict__ yf)
{
  const int n = blockIdx.y;
  const int I = blockIdx.x;
  __shared__ float4 Ul[64*16];    // 64 rows x 32 complex, XOR-swizzled 16B units
  __shared__ float4 Vl[128*16];
  const int t = threadIdx.x;
  const int ty = t >> 4, tx = t & 15;
  float2 acc[4][8];
  #pragma unroll
  for (int rr = 0; rr < 4; rr++)
    #pragma unroll
    for (int jj = 0; jj < 8; jj++) acc[rr][jj] = make_float2(0.f, 0.f);

  const size_t ubase = (size_t)n*8192 + (size_t)I*4096;
  const size_t vbase = (size_t)n*8192;
  #pragma unroll
  for (int half = 0; half < 2; half++){
    const int ch = half*32;
    for (int k = 0; k < 4; k++){
      int fe = t + (k<<8);               // 0..1023
      int r = fe >> 4, u = fe & 15;
      float4 v = *(const float4*)&uf[ubase + (size_t)r*64 + ch + (u<<1)];
      Ul[(r<<4) + (u ^ ((r>>2)&7))] = v;
    }
    for (int k = 0; k < 8; k++){
      int fe = t + (k<<8);               // 0..2047
      int r = fe >> 4, u = fe & 15;
      float4 v = *(const float4*)&vf[vbase + (size_t)r*64 + ch + (u<<1)];
      Vl[(r<<4) + (u ^ ((r>>2)&7))] = v;
    }
    __syncthreads();
    #pragma unroll
    for (int cc = 0; cc < 8; cc++){
      float4 ua[4][2];
      #pragma unroll
      for (int rr = 0; rr < 4; rr++){
        int r = (ty<<2) + rr;
        int p = (r>>2) & 7;
        ua[rr][0] = Ul[(r<<4) + (((cc<<1)  ) ^ p)];
        ua[rr][1] = Ul[(r<<4) + (((cc<<1)+1) ^ p)];
      }
      #pragma unroll
      for (int jj = 0; jj < 8; jj++){
        int r = (tx<<3) + jj;
        int p = (r>>2) & 7;
        float4 v0 = Vl[(r<<4) + (((cc<<1)  ) ^ p)];
        float4 v1 = Vl[(r<<4) + (((cc<<1)+1) ^ p)];
        float2 bb0 = make_float2(v0.x,v0.y), bb1 = make_float2(v0.z,v0.w);
        float2 bb2 = make_float2(v1.x,v1.y), bb3 = make_float2(v1.z,v1.w);
        #pragma unroll
        for (int rr = 0; rr < 4; rr++){
          float2 a0 = make_float2(ua[rr][0].x, ua[rr][0].y);
          float2 a1 = make_float2(ua[rr][0].z, ua[rr][0].w);
          float2 a2 = make_float2(ua[rr][1].x, ua[rr][1].y);
          float2 a3 = make_float2(ua[rr][1].z, ua[rr][1].w);
          acc[rr][jj].x += a0.x*bb0.x - a0.y*bb0.y;
          acc[rr][jj].y += a0.x*bb0.y + a0.y*bb0.x;
          acc[rr][jj].x += a1.x*bb1.x - a1.y*bb1.y;
          acc[rr][jj].y += a1.x*bb1.y + a1.y*bb1.x;
          acc[rr][jj].x += a2.x*bb2.x - a2.y*bb2.y;
          acc[rr][jj].y += a2.x*bb2.y + a2.y*bb2.x;
          acc[rr][jj].x += a3.x*bb3.x - a3.y*bb3.y;
          acc[rr][jj].y += a3.x*bb3.y + a3.y*bb3.x;
        }
      }
    }
    __syncthreads();
  }
  #pragma unroll
  for (int rr = 0; rr < 4; rr++){
    size_t row = (size_t)n*16384 + (size_t)(I*64 + (ty<<2) + rr)*128 + (tx<<3);
    #pragma unroll
    for (int jj = 0; jj < 8; jj += 2){
      *(float4*)&yf[row + jj] =
        make_float4(acc[rr][jj].x, acc[rr][jj].y, acc[rr][jj+1].x, acc[rr][jj+1].y);
    }
  }
}

// ---------------- inverse real FFT + abs/log1p + InstanceNorm; out signal-major ----------------
__global__ __launch_bounds__(256) void ifft_post(
    const float2* __restrict__ yf, float* __restrict__ yout,
    const float2* __restrict__ tw2k, const float2* __restrict__ tw4k)
{
  __shared__ __align__(16) float2 Z[4*2048];
  const int t = threadIdx.x;
  const int q = t >> 6, tl = t & 63;
  const size_t s0 = (size_t)blockIdx.x*4;
  const float ksc = 1.0f/4096.0f;            // 0.5 (pack) * 1/2048 (ifft)
  for (int it = 0; it < 16; it++){
    int idx = (it<<8) + t;
    int n = idx >> 2, qq = idx & 3;
    float2 P = yf[(size_t)n*16384 + s0 + qq];
    float2 Q = yf[(size_t)(2048 - n)*16384 + s0 + qq];
    float2 W = tw4k[n];
    float Ex = ksc*(P.x + Q.x), Ey = ksc*(P.y - Q.y);
    float Dx = ksc*(P.x - Q.x), Dy = ksc*(P.y + Q.y);
    float Ox = W.x*Dx + W.y*Dy;              // O = conj(W)*D
    float Oy = W.x*Dy - W.y*Dx;
    float2* Zs = Z + (qq << 11);
    Zs[__brev((unsigned)n) >> 21] = make_float2(Ex - Oy, Ey + Ox);         // Z[n] = E + iO
    if (n)
      Zs[__brev((unsigned)(2048 - n)) >> 21] = make_float2(Ex + Oy, Ox - Ey); // Z[M-n] = conj(E-iO)
  }
  if (t < 4){
    float2 P = yf[1024ull*16384 + s0 + t];
    float2 W = tw4k[1024];                   // (0,-1)
    float Ex = ksc*2.f*P.x;
    float Dy = ksc*2.f*P.y;
    float Ox = W.y*Dy;                       // = -Dy
    Z[(t<<11) + (__brev(1024u) >> 21)] = make_float2(Ex, Ox);
  }
  __syncthreads();
  float2* Zq = Z + (q << 11);
  fft2048<1>(Zq, tl, tw2k);
  float sum = 0.f, ss = 0.f;
  for (int k = 0; k < 32; k++){
    int i = (tl<<5) + k;
    float2 z = Zq[i];
    float a = __logf(1.f + fabsf(z.x));      // log1p(relu(abs(.)))
    float b = __logf(1.f + fabsf(z.y));
    Zq[i] = make_float2(a, b);
    sum += a + b;
    ss  += a*a + b*b;
  }
  #pragma unroll
  for (int o = 32; o > 0; o >>= 1){
    sum += __shfl_down(sum, o);
    ss  += __shfl_down(ss, o);
  }
  sum = __shfl(sum, 0);
  ss  = __shfl(ss, 0);
  const float mean = sum * (1.f/4096.f);
  const float var  = ss  * (1.f/4096.f) - mean*mean;
  const float rstd = rsqrtf(var + 1e-5f);
  float2* op = (float2*)(yout + (s0 + q)*4096);
  for (int k = 0; k < 32; k++){
    int i = (tl<<5) + k;
    float2 z = Zq[i];
    op[i] = make_float2((z.x - mean)*rstd, (z.y - mean)*rstd);
  }
}

// ---------------- final interleave: out[b][h][ni*16+ti] = yout[(ti*8+b)*128+h][ni] ----------------
__global__ __launch_bounds__(256) void rearrange_out(const float* __restrict__ yin, float* __restrict__ out){
  __shared__ __align__(16) float tile[512*17];
  int blk = blockIdx.x;
  int ch = blk & 7, h = (blk>>3) & 127, bi = blk>>10;
  int ni0 = ch*512;
  int t = threadIdx.x;
  for (int k = 0; k < 8; k++){
    int idx = t + (k<<8);                    // 0..2047 float4 units
    int ti = idx >> 7, f4c = idx & 127;
    float4 v = *(const float4*)&yin[((size_t)((ti*8 + bi)*128 + h))*4096 + ni0 + 4*f4c];
    int ni = 4*f4c;
    tile[(ni+0)*17 + ti] = v.x;
    tile[(ni+1)*17 + ti] = v.y;
    tile[(ni+2)*17 + ti] = v.z;
    tile[(ni+3)*17 + ti] = v.w;
  }
  __syncthreads();
  float* op = out + ((size_t)(bi*128 + h))*65536 + (size_t)ni0*16;
  for (int k = 0; k < 8; k++){
    int e = t + (k<<8);                      // 0..2047 float4 units
    int ni = e >> 2, ti0 = (e & 3) * 4;
    float4 v = make_float4(tile[ni*17 + ti0 + 0], tile[ni*17 + ti0 + 1],
                           tile[ni*17 + ti0 + 2], tile[ni*17 + ti0 + 3]);
    *(float4*)&op[4*e] = v;
  }
}

extern "C" void kernel_launch(void* const* d_in, const int* in_sizes, int n_in,
                              void* d_out, int out_size, void* d_ws, size_t ws_size,
                              hipStream_t stream)
{
  const float* X = (const float*)d_in[0];       // (8,64,65536)
  const float* F = (const float*)d_in[1];       // (128,64,1023)
  float* out = (float*)d_out;                   // (8,128,65536)
  char* ws = (char*)d_ws;
  float2* uf   = (float2*)(ws);
  float2* vf   = (float2*)(ws + OFS_VF);
  float2* yf   = (float2*)(ws + OFS_YF);
  float*  Xt   = (float*) (ws + OFS_YF);        // aliases yf (consumed before GEMM writes yf)
  float*  yout = (float*) (ws);                 // aliases uf+vf (written after both consumed)
  float2* tw2k = (float2*)(ws + OFS_TW2K);
  float2* tw4k = (float2*)(ws + OFS_TW4K);

  tw_init<<<9, 256, 0, stream>>>(tw2k, tw4k);
  decimate_x<<<8192, 64, 0, stream>>>(X, Xt);
  fft_fwd<<<2048, 256, 0, stream>>>(Xt, 4096, 0, uf, tw2k, tw4k);
  fft_fwd<<<2048, 256, 0, stream>>>(F, 1023, 1, vf, tw2k, tw4k);
  dim3 g3(2, 2049);
  gemm_bins<<<g3, 256, 0, stream>>>(uf, vf, yf);
  ifft_post<<<4096, 256, 0, stream>>>(yf, yout, tw2k, tw4k);
  rearrange_out<<<8192, 256, 0, stream>>>(yout, out);
}

// Round 2
// 1224.507 us; speedup vs baseline: 1.5121x; 1.5121x over previous
//
#include <hip/hip_runtime.h>
#include <math.h>

#define R2C 0.70710678118654752440f

// ---------------- workspace layout (bytes) ----------------
// u_f : 2049*8192*8  = 134,283,264   at 0          (later: yout, 268,435,456 B over u_f+v_f)
// v_f : 134,283,264                  at OFS_VF
// y_f : 2049*16384*8 = 268,566,528   at OFS_YF     (Xt aliases here before GEMM, 134,217,728 B)
// tw2k: 1024 float2                  at OFS_TW2K
// tw4k: 2049 float2                  at OFS_TW4K
#define OFS_VF   134283264ull
#define OFS_YF   268566528ull
#define OFS_TW2K 537133056ull
#define OFS_TW4K 537141248ull

typedef __attribute__((ext_vector_type(8))) short bf16x8;
typedef __attribute__((ext_vector_type(4))) float f32x4;

__device__ __forceinline__ float2 cmulf(float2 a, float2 b){
  return make_float2(a.x*b.x - a.y*b.y, a.x*b.y + a.y*b.x);
}
__device__ __forceinline__ float2 caddf(float2 a, float2 b){ return make_float2(a.x+b.x, a.y+b.y); }
__device__ __forceinline__ float2 csubf(float2 a, float2 b){ return make_float2(a.x-b.x, a.y-b.y); }

// multiply by -i (forward) / +i (inverse)
template<int INV>
__device__ __forceinline__ float2 rot90(float2 a){
  return INV ? make_float2(-a.y, a.x) : make_float2(a.y, -a.x);
}
template<int INV>
__device__ __forceinline__ float2 twld(const float2* __restrict__ tw, int idx){
  float2 w = tw[idx];
  return INV ? make_float2(w.x, -w.y) : w;
}

// round-to-nearest-even fp32 -> bf16 bits
__device__ __forceinline__ unsigned bf16rn(float x){
  unsigned u = __float_as_uint(x);
  return (u + 0x7FFFu + ((u >> 16) & 1u)) >> 16;
}

// ---------------- twiddle init ----------------
__global__ void tw_init(float2* tw2k, float2* tw4k){
  int t = blockIdx.x*256 + threadIdx.x;
  if (t < 1024){
    double th = -6.283185307179586476925286766559 * (double)t / 2048.0;
    tw2k[t] = make_float2((float)cos(th), (float)sin(th));
  }
  if (t < 2049){
    double th = -6.283185307179586476925286766559 * (double)t / 4096.0;
    tw4k[t] = make_float2((float)cos(th), (float)sin(th));
  }
}

// ---------------- decimation transpose: X[b][c][ni*16+ti] -> Xt[(ti*8+b)*64+c][ni] ----------------
__global__ __launch_bounds__(64) void decimate_x(const float* __restrict__ X, float* __restrict__ Xt){
  __shared__ __align__(16) float tile[16*260];   // [ti][ni] padded
  int blk = blockIdx.x;
  int nc = blk & 15, c = (blk>>4) & 63, bi = blk>>10;
  const float* src = X + ((size_t)(bi*64 + c))*65536 + (size_t)nc*4096;
  int t = threadIdx.x;  // 64
  for (int k = 0; k < 16; k++){
    float4 v = *(const float4*)&src[4*(t + (k<<6))];
    int j = 4*(t + (k<<6));
    int ni = j >> 4;            // 0..255
    int ti0 = j & 15;           // 0,4,8,12
    tile[(ti0+0)*260 + ni] = v.x;
    tile[(ti0+1)*260 + ni] = v.y;
    tile[(ti0+2)*260 + ni] = v.z;
    tile[(ti0+3)*260 + ni] = v.w;
  }
  __syncthreads();
  for (int ti = 0; ti < 16; ti++){
    float4 v = *(const float4*)&tile[ti*260 + 4*t];
    size_t s = (size_t)((ti*8 + bi)*64 + c);
    *(float4*)&Xt[s*4096 + nc*256 + 4*t] = v;
  }
}

// ---------------- 2048-pt complex FFT core (DIT, bit-reversed input in LDS) ----------------
template<int INV>
__device__ void fft2048(float2* Zq, int tl, const float2* __restrict__ tw2k){
  {
    const float2 W81 = INV ? make_float2(R2C,  R2C) : make_float2(R2C, -R2C);
    const float2 W83 = INV ? make_float2(-R2C, R2C) : make_float2(-R2C, -R2C);
    for (int r = 0; r < 4; r++){
      float4* p4 = (float4*)(Zq + ((tl + (r<<6)) << 3));
      float4 v0 = p4[0], v1 = p4[1], v2 = p4[2], v3 = p4[3];
      float2 a0 = make_float2(v0.x,v0.y), a1 = make_float2(v0.z,v0.w);
      float2 a2 = make_float2(v1.x,v1.y), a3 = make_float2(v1.z,v1.w);
      float2 a4 = make_float2(v2.x,v2.y), a5 = make_float2(v2.z,v2.w);
      float2 a6 = make_float2(v3.x,v3.y), a7 = make_float2(v3.z,v3.w);
      float2 b0 = caddf(a0,a1), b1 = csubf(a0,a1);
      float2 b2 = caddf(a2,a3), b3 = csubf(a2,a3);
      float2 b4 = caddf(a4,a5), b5 = csubf(a4,a5);
      float2 b6 = caddf(a6,a7), b7 = csubf(a6,a7);
      float2 c0 = caddf(b0,b2), c2 = csubf(b0,b2);
      float2 tt = rot90<INV>(b3);
      float2 c1 = caddf(b1,tt), c3 = csubf(b1,tt);
      float2 c4 = caddf(b4,b6), c6 = csubf(b4,b6);
      tt = rot90<INV>(b7);
      float2 c5 = caddf(b5,tt), c7 = csubf(b5,tt);
      float2 d0 = caddf(c0,c4), d4 = csubf(c0,c4);
      tt = cmulf(W81, c5);
      float2 d1 = caddf(c1,tt), d5 = csubf(c1,tt);
      tt = rot90<INV>(c6);
      float2 d2 = caddf(c2,tt), d6 = csubf(c2,tt);
      tt = cmulf(W83, c7);
      float2 d3 = caddf(c3,tt), d7 = csubf(c3,tt);
      p4[0] = make_float4(d0.x,d0.y,d1.x,d1.y);
      p4[1] = make_float4(d2.x,d2.y,d3.x,d3.y);
      p4[2] = make_float4(d4.x,d4.y,d5.x,d5.y);
      p4[3] = make_float4(d6.x,d6.y,d7.x,d7.y);
    }
  }
  __syncthreads();
  #pragma unroll
  for (int s = 4; s <= 10; s += 2){
    const int hh = 1 << (s-1);
    const int sh2 = 11 - s, sh4 = 10 - s;
    for (int r = 0; r < 8; r++){
      int fm = tl + (r<<6);                 // 0..511
      int j  = fm & (hh-1);
      int i0 = ((fm >> (s-1)) << (s+1)) + j;
      float2 a = Zq[i0], b = Zq[i0+hh], c = Zq[i0+2*hh], d = Zq[i0+3*hh];
      float2 Wa = twld<INV>(tw2k, j << sh2);
      float2 Wb = twld<INV>(tw2k, j << sh4);
      float2 wb = cmulf(Wa,b), wd = cmulf(Wa,d);
      float2 t0 = caddf(a,wb), t1 = csubf(a,wb);
      float2 t2 = caddf(c,wd), t3 = csubf(c,wd);
      float2 u0 = cmulf(Wb,t2);
      float2 u1 = rot90<INV>(cmulf(Wb,t3));
      Zq[i0]      = caddf(t0,u0);
      Zq[i0+2*hh] = csubf(t0,u0);
      Zq[i0+hh]   = caddf(t1,u1);
      Zq[i0+3*hh] = csubf(t1,u1);
    }
    __syncthreads();
  }
}

// ---------------- forward real-4096 FFT: 4 signals/block, output bin-major dst[n*8192 + s] ----------------
__global__ __launch_bounds__(256) void fft_fwd(
    const float* __restrict__ src, int row_len, int conj_out,
    float2* __restrict__ dst,
    const float2* __restrict__ tw2k, const float2* __restrict__ tw4k)
{
  __shared__ __align__(16) float2 Z[4*2048];   // 64 KB
  const int t = threadIdx.x;
  const int q = t >> 6, tl = t & 63;
  const size_t s = (size_t)blockIdx.x*4 + q;
  float2* Zq = Z + (q << 11);
  if (row_len == 4096){
    const float2* xp = (const float2*)(src + s*4096);
    for (int k = 0; k < 32; k++){
      int j = tl + (k<<6);
      Zq[__brev((unsigned)j) >> 21] = xp[j];
    }
  } else {
    const float* xp = src + s*(size_t)row_len;
    for (int k = 0; k < 32; k++){
      int j = tl + (k<<6);
      int j2 = j << 1;
      float x0 = (j2     < row_len) ? xp[j2]   : 0.f;
      float x1 = (j2 + 1 < row_len) ? xp[j2+1] : 0.f;
      Zq[__brev((unsigned)j) >> 21] = make_float2(x0, x1);
    }
  }
  __syncthreads();
  fft2048<0>(Zq, tl, tw2k);
  const size_t base = (size_t)blockIdx.x*4;
  for (int it = 0; it < 32; it++){
    int idx = (it<<8) + t;
    int n = idx >> 2, qq = idx & 3;
    const float2* Zs = Z + (qq << 11);
    float2 P = Zs[n];
    float2 Q = Zs[(2048 - n) & 2047];
    float2 W = tw4k[n];
    float Ex = 0.5f*(P.x + Q.x), Ey = 0.5f*(P.y - Q.y);
    float Dx = 0.5f*(P.x - Q.x), Dy = 0.5f*(P.y + Q.y);
    float WDx = W.x*Dx - W.y*Dy;
    float WDy = W.x*Dy + W.y*Dx;
    float2 Xn = make_float2(Ex + WDy, conj_out ? (WDx - Ey) : (Ey - WDx));
    dst[(size_t)n*8192 + base + qq] = Xn;
  }
  if (t < 4){
    float2 Z0 = Z[t << 11];
    dst[2048ull*8192 + base + t] = make_float2(Z0.x - Z0.y, 0.f);   // Nyquist (real)
  }
}

// ---------------- per-bin complex GEMM on MFMA, split-bf16 (hi/lo) ----------------
// Real view: Y[s][j] = sum_k A[s][k]*B[k][j]; M=128 (s=tb), N=256 (j=2h+e), K=128 (k=2c+d)
//   A[s][2c]=Ure, A[s][2c+1]=Uim  (== uf natural layout as floats)
//   B[2c][2h]=Vre, B[2c+1][2h]=-Vim, B[2c][2h+1]=Vim, B[2c+1][2h+1]=Vre
// Split: Y ~= Ah*Bh + Ah*Bl + Al*Bh. Block: 128(M) x 128(N half I), 4 waves of 64x64.
__global__ __launch_bounds__(256) void gemm_mfma(
    const float* __restrict__ uff, const float* __restrict__ vff,
    float* __restrict__ yff)
{
  __shared__ __align__(16) unsigned short lds[4*128*72];  // Ah,Al,Bh,Bl planes (73,728 B)
  unsigned short* Ah = lds;
  unsigned short* Al = lds + 9216;
  unsigned short* Bh = lds + 18432;
  unsigned short* Bl = lds + 27648;
  const int n = blockIdx.y;
  const int I = blockIdx.x;
  const int t = threadIdx.x;
  const int lane = t & 63, w = t >> 6;
  const int wm = w & 1, wn = w >> 1;
  const int lm = lane & 15, lq = lane >> 4;

  f32x4 acc[4][4];
  #pragma unroll
  for (int mi = 0; mi < 4; mi++)
    #pragma unroll
    for (int ni = 0; ni < 4; ni++) acc[mi][ni] = (f32x4)0.f;

  const float4* uf4 = (const float4*)uff;
  const float4* vf4 = (const float4*)vff;

  #pragma unroll
  for (int kt = 0; kt < 2; kt++){
    if (kt) __syncthreads();
    const int c0h = kt*16;    // k-tile offset in float4 units (16 f4 = 32 floats = 16 complex)
    // ---- stage A (128 rows x 32 floats): 2048 float4 loads ----
    #pragma unroll
    for (int k = 0; k < 8; k++){
      int idx = t + (k<<8);
      int row = idx >> 4, cc = idx & 15;
      float4 v = uf4[(size_t)n*4096 + row*32 + c0h + cc];
      unsigned hx = bf16rn(v.x), hy = bf16rn(v.y), hz = bf16rn(v.z), hw = bf16rn(v.w);
      float lx = v.x - __uint_as_float(hx<<16);
      float ly = v.y - __uint_as_float(hy<<16);
      float lz = v.z - __uint_as_float(hz<<16);
      float lw = v.w - __uint_as_float(hw<<16);
      unsigned gx = bf16rn(lx), gy = bf16rn(ly), gz = bf16rn(lz), gw = bf16rn(lw);
      *(uint2*)&Ah[row*72 + 4*cc] = make_uint2(hx | (hy<<16), hz | (hw<<16));
      *(uint2*)&Al[row*72 + 4*cc] = make_uint2(gx | (gy<<16), gz | (gw<<16));
    }
    // ---- stage B (64 h-rows -> 128 j-rows x 32 floats): 1024 float4 loads ----
    #pragma unroll
    for (int k = 0; k < 4; k++){
      int idx = t + (k<<8);
      int hr = idx >> 4, cc = idx & 15;
      float4 v = vf4[(size_t)n*4096 + (I*64 + hr)*32 + c0h + cc];
      unsigned hx = bf16rn(v.x), hy = bf16rn(v.y), hz = bf16rn(v.z), hw = bf16rn(v.w);
      float lx = v.x - __uint_as_float(hx<<16);
      float ly = v.y - __uint_as_float(hy<<16);
      float lz = v.z - __uint_as_float(hz<<16);
      float lw = v.w - __uint_as_float(hw<<16);
      unsigned gx = bf16rn(lx), gy = bf16rn(ly), gz = bf16rn(lz), gw = bf16rn(lw);
      // row 2h:   (re, -im, re, -im) ; row 2h+1: (im, re, im, re)
      *(uint2*)&Bh[(2*hr  )*72 + 4*cc] = make_uint2(hx | ((hy^0x8000u)<<16), hz | ((hw^0x8000u)<<16));
      *(uint2*)&Bh[(2*hr+1)*72 + 4*cc] = make_uint2(hy | (hx<<16), hw | (hz<<16));
      *(uint2*)&Bl[(2*hr  )*72 + 4*cc] = make_uint2(gx | ((gy^0x8000u)<<16), gz | ((gw^0x8000u)<<16));
      *(uint2*)&Bl[(2*hr+1)*72 + 4*cc] = make_uint2(gy | (gx<<16), gw | (gz<<16));
    }
    __syncthreads();
    // ---- 3 split passes x 2 K-steps of 32 ----
    #pragma unroll
    for (int pass = 0; pass < 3; pass++){
      const unsigned short* Ap = (pass == 2) ? Al : Ah;
      const unsigned short* Bp = (pass == 1) ? Bl : Bh;
      #pragma unroll
      for (int ks = 0; ks < 2; ks++){
        const int kb = ks*32 + (lq<<3);
        bf16x8 af[4], bfr[4];
        #pragma unroll
        for (int mi = 0; mi < 4; mi++)
          af[mi] = *(const bf16x8*)&Ap[(64*wm + 16*mi + lm)*72 + kb];
        #pragma unroll
        for (int ni = 0; ni < 4; ni++)
          bfr[ni] = *(const bf16x8*)&Bp[(64*wn + 16*ni + lm)*72 + kb];
        #pragma unroll
        for (int mi = 0; mi < 4; mi++)
          #pragma unroll
          for (int ni = 0; ni < 4; ni++)
            acc[mi][ni] = __builtin_amdgcn_mfma_f32_16x16x32_bf16(af[mi], bfr[ni], acc[mi][ni], 0, 0, 0);
      }
    }
  }
  // ---- epilogue: C/D layout col=lane&15, row=lq*4+reg ----
  #pragma unroll
  for (int mi = 0; mi < 4; mi++){
    #pragma unroll
    for (int ni = 0; ni < 4; ni++){
      int j = I*128 + 64*wn + 16*ni + lm;
      #pragma unroll
      for (int r = 0; r < 4; r++){
        int srow = 64*wm + 16*mi + (lq<<2) + r;
        yff[(size_t)n*32768 + (size_t)srow*256 + j] = acc[mi][ni][r];
      }
    }
  }
}

// ---------------- inverse real FFT + abs/log1p + InstanceNorm; out signal-major ----------------
__global__ __launch_bounds__(256) void ifft_post(
    const float2* __restrict__ yf, float* __restrict__ yout,
    const float2* __restrict__ tw2k, const float2* __restrict__ tw4k)
{
  __shared__ __align__(16) float2 Z[4*2048];
  const int t = threadIdx.x;
  const int q = t >> 6, tl = t & 63;
  const size_t s0 = (size_t)blockIdx.x*4;
  const float ksc = 1.0f/4096.0f;
  for (int it = 0; it < 16; it++){
    int idx = (it<<8) + t;
    int n = idx >> 2, qq = idx & 3;
    float2 P = yf[(size_t)n*16384 + s0 + qq];
    float2 Q = yf[(size_t)(2048 - n)*16384 + s0 + qq];
    float2 W = tw4k[n];
    float Ex = ksc*(P.x + Q.x), Ey = ksc*(P.y - Q.y);
    float Dx = ksc*(P.x - Q.x), Dy = ksc*(P.y + Q.y);
    float Ox = W.x*Dx + W.y*Dy;
    float Oy = W.x*Dy - W.y*Dx;
    float2* Zs = Z + (qq << 11);
    Zs[__brev((unsigned)n) >> 21] = make_float2(Ex - Oy, Ey + Ox);
    if (n)
      Zs[__brev((unsigned)(2048 - n)) >> 21] = make_float2(Ex + Oy, Ox - Ey);
  }
  if (t < 4){
    float2 P = yf[1024ull*16384 + s0 + t];
    float Ex = ksc*2.f*P.x;
    float Dy = ksc*2.f*P.y;
    Z[(t<<11) + (__brev(1024u) >> 21)] = make_float2(Ex, -Dy);
  }
  __syncthreads();
  float2* Zq = Z + (q << 11);
  fft2048<1>(Zq, tl, tw2k);
  float sum = 0.f, ss = 0.f;
  for (int k = 0; k < 32; k++){
    int i = (tl<<5) + k;
    float2 z = Zq[i];
    float a = __logf(1.f + fabsf(z.x));
    float b = __logf(1.f + fabsf(z.y));
    Zq[i] = make_float2(a, b);
    sum += a + b;
    ss  += a*a + b*b;
  }
  #pragma unroll
  for (int o = 32; o > 0; o >>= 1){
    sum += __shfl_down(sum, o);
    ss  += __shfl_down(ss, o);
  }
  sum = __shfl(sum, 0);
  ss  = __shfl(ss, 0);
  const float mean = sum * (1.f/4096.f);
  const float var  = ss  * (1.f/4096.f) - mean*mean;
  const float rstd = rsqrtf(var + 1e-5f);
  float2* op = (float2*)(yout + (s0 + q)*4096);
  for (int k = 0; k < 32; k++){
    int i = (tl<<5) + k;
    float2 z = Zq[i];
    op[i] = make_float2((z.x - mean)*rstd, (z.y - mean)*rstd);
  }
}

// ---------------- final interleave: out[b][h][ni*16+ti] = yout[(ti*8+b)*128+h][ni] ----------------
__global__ __launch_bounds__(256) void rearrange_out(const float* __restrict__ yin, float* __restrict__ out){
  __shared__ __align__(16) float tile[512*17];
  int blk = blockIdx.x;
  int ch = blk & 7, h = (blk>>3) & 127, bi = blk>>10;
  int ni0 = ch*512;
  int t = threadIdx.x;
  for (int k = 0; k < 8; k++){
    int idx = t + (k<<8);
    int ti = idx >> 7, f4c = idx & 127;
    float4 v = *(const float4*)&yin[((size_t)((ti*8 + bi)*128 + h))*4096 + ni0 + 4*f4c];
    int ni = 4*f4c;
    tile[(ni+0)*17 + ti] = v.x;
    tile[(ni+1)*17 + ti] = v.y;
    tile[(ni+2)*17 + ti] = v.z;
    tile[(ni+3)*17 + ti] = v.w;
  }
  __syncthreads();
  float* op = out + ((size_t)(bi*128 + h))*65536 + (size_t)ni0*16;
  for (int k = 0; k < 8; k++){
    int e = t + (k<<8);
    int ni = e >> 2, ti0 = (e & 3) * 4;
    float4 v = make_float4(tile[ni*17 + ti0 + 0], tile[ni*17 + ti0 + 1],
                           tile[ni*17 + ti0 + 2], tile[ni*17 + ti0 + 3]);
    *(float4*)&op[4*e] = v;
  }
}

extern "C" void kernel_launch(void* const* d_in, const int* in_sizes, int n_in,
                              void* d_out, int out_size, void* d_ws, size_t ws_size,
                              hipStream_t stream)
{
  const float* X = (const float*)d_in[0];       // (8,64,65536)
  const float* F = (const float*)d_in[1];       // (128,64,1023)
  float* out = (float*)d_out;                   // (8,128,65536)
  char* ws = (char*)d_ws;
  float2* uf   = (float2*)(ws);
  float2* vf   = (float2*)(ws + OFS_VF);
  float2* yf   = (float2*)(ws + OFS_YF);
  float*  Xt   = (float*) (ws + OFS_YF);        // aliases yf (consumed before GEMM writes yf)
  float*  yout = (float*) (ws);                 // aliases uf+vf (written after both consumed)
  float2* tw2k = (float2*)(ws + OFS_TW2K);
  float2* tw4k = (float2*)(ws + OFS_TW4K);

  tw_init<<<9, 256, 0, stream>>>(tw2k, tw4k);
  decimate_x<<<8192, 64, 0, stream>>>(X, Xt);
  fft_fwd<<<2048, 256, 0, stream>>>(Xt, 4096, 0, uf, tw2k, tw4k);
  fft_fwd<<<2048, 256, 0, stream>>>(F, 1023, 1, vf, tw2k, tw4k);
  dim3 g3(2, 2049);
  gemm_mfma<<<g3, 256, 0, stream>>>((const float*)uf, (const float*)vf, (float*)yf);
  ifft_post<<<4096, 256, 0, stream>>>(yf, yout, tw2k, tw4k);
  rearrange_out<<<8192, 256, 0, stream>>>(yout, out);
}